// Round 11
// baseline (302.649 us; speedup 1.0000x reference)
//
#include <hip/hip_runtime.h>
#include <hip/hip_bf16.h>

typedef unsigned int u32;
typedef unsigned short u16;
typedef short short8 __attribute__((ext_vector_type(8)));
typedef float f32x4 __attribute__((ext_vector_type(4)));

#define R_ 32
#define SORT_STRIDE 1024    // per-tile bucket slots (mean ~773, +9 sigma)
#define CAP 12              // per-wave per-relation buffered gathers (mean ~6)
#define MAXU 16384          // max unique scored nodes (2*T)
#define NSPLIT 4            // relation-group split
#define NRG 8               // relations per group (R_/NSPLIT)

static __device__ __forceinline__ u16 f2bf(float f) {
  u32 u = __float_as_uint(f);
  u = (u + 0x7FFFu + ((u >> 16) & 1u)) >> 16;   // RNE
  return (u16)u;
}
static __device__ __forceinline__ u32 pk2(float a, float b) {
  __hip_bfloat162 h2 = __float22bfloat162_rn(make_float2(a, b));
  union { __hip_bfloat162 h; u32 u; } cv; cv.h = h2; return cv.u;
}

// ---- K1: x convert + W pack (LDS transpose) + mark/compact ----
// map pre-filled -1, cnt pre-filled -1, bcnt pre-filled -1 (one 0xFF memset).
__global__ __launch_bounds__(256) void k_prep(
    const float* __restrict__ x, const float* __restrict__ W,
    const float* __restrict__ Wroot, u16* __restrict__ xb,
    u16* __restrict__ wp, u16* __restrict__ wrootp,
    const int* __restrict__ head, const int* __restrict__ tail,
    int* __restrict__ map, int* __restrict__ inv, int* __restrict__ cnt,
    int n4, int convNB, int T) {
  __shared__ u32 lds[8192];   // 32 KB: one 128x128 bf16 matrix
  int bx = blockIdx.x;
  const int t = threadIdx.x;
  if (bx < convNB) {
    int i = bx * 256 + t;
    if (i >= n4) return;
    const float4 f = ((const float4*)x)[i];
    u32 lo = (u32)f2bf(f.x) | ((u32)f2bf(f.y) << 16);
    u32 hi = (u32)f2bf(f.z) | ((u32)f2bf(f.w) << 16);
    ((uint2*)xb)[i] = make_uint2(lo, hi);
    return;
  }
  bx -= convNB;
  if (bx < 33) {
    const int rr = bx;
    const float* src = (rr < 32) ? (W + (size_t)rr * (128 * 128)) : Wroot;
#pragma unroll
    for (int k = 0; k < 16; ++k) {
      const int fi = k * 256 + t;
      const float4 f = ((const float4*)src)[fi];
      u32 lo = (u32)f2bf(f.x) | ((u32)f2bf(f.y) << 16);
      u32 hi = (u32)f2bf(f.z) | ((u32)f2bf(f.w) << 16);
      ((uint2*)lds)[fi] = make_uint2(lo, hi);
    }
    __syncthreads();
    const u16* l16 = (const u16*)lds;
#pragma unroll
    for (int p = 0; p < 8; ++p) {
      const int v = p * 256 + t;
      const int lane = v & 63, ks = (v >> 6) & 3, ct = v >> 8;
      const int i0 = ks * 32 + (lane >> 4) * 8;
      const int o  = ct * 16 + (lane & 15);
      u32 w01 = (u32)l16[(i0 + 0) * 128 + o] | ((u32)l16[(i0 + 1) * 128 + o] << 16);
      u32 w23 = (u32)l16[(i0 + 2) * 128 + o] | ((u32)l16[(i0 + 3) * 128 + o] << 16);
      u32 w45 = (u32)l16[(i0 + 4) * 128 + o] | ((u32)l16[(i0 + 5) * 128 + o] << 16);
      u32 w67 = (u32)l16[(i0 + 6) * 128 + o] | ((u32)l16[(i0 + 7) * 128 + o] << 16);
      u16* dst = (rr < 32) ? (wp + ((size_t)((rr * 8 + ct) * 4 + ks) * 64 + lane) * 8)
                           : (wrootp + ((size_t)((ct * 4 + ks) * 64 + lane)) * 8);
      *(uint4*)dst = make_uint4(w01, w23, w45, w67);
    }
    return;
  }
  bx -= 33;
  int i = bx * 256 + t;
  if (i >= 2 * T) return;
  int n = (i < T) ? head[i] : tail[i - T];
  if (atomicCAS(map + n, -1, -2) == -1) {
    int c = atomicAdd(cnt, 1) + 1;   // cnt starts at -1 -> first ticket 0
    inv[c] = n;
    map[n] = c;
  }
}

// ---- K2: bin kept edges into per-tile buckets (no global sort needed) ----
// packed: src(16b) | row-in-tile(6b)<<16 | rel(5b)<<22.  bcnt init -1.
__global__ void k_bin(const int* __restrict__ ei, const int* __restrict__ et,
                      const int* __restrict__ map,
                      int* __restrict__ bcnt, u32* __restrict__ bins, int E) {
  int e = blockIdx.x * 256 + threadIdx.x;
  if (e >= E) return;
  int mt = map[ei[E + e]];
  if (mt < 0) return;
  int p = atomicAdd(bcnt + (mt >> 6), 1) + 1;
  if (p < SORT_STRIDE)
    bins[(size_t)(mt >> 6) * SORT_STRIDE + p] =
        ((u32)ei[e] & 0xFFFFu) | ((u32)(mt & 63) << 16) | ((u32)et[e] << 22);
}

// ---- K3: batch kernel with IN-BLOCK LDS counting sort ----
// Block (b, qs): tile b (64 compact nodes) x relation group qs (8 rels).
// 1) load tile bucket, LDS-hist the 512 keys (wg,rel-in-group,row) of own
//    group, wave-scan, LDS-scatter into sortedL (group-local order).
// 2) round-7 phase loop (2 barriers/phase, single aggb), srt reads from LDS.
// Replaces the global hist+scan+scatter dispatches entirely.
#define PHASE(RR, RI, XV, EVB)                                                 \
  {                                                                            \
    const int r = (RR);                                                        \
    const int Er = __builtin_amdgcn_readlane(eAll, (RI));                      \
    _Pragma("unroll") for (int rr = 0; rr < 16; ++rr)                          \
        *(u32*)(aggb + (size_t)(w * 16 + rr) * 136 + 2 * lane) = 0;            \
    {                                                                          \
      const int nB = min(Er - sCur, CAP);                                      \
      int curRow = -1, rc = 0;                                                 \
      float v0 = 0.f, v1 = 0.f;                                                \
      _Pragma("unroll") for (int j = 0; j < CAP; ++j) {                        \
        if (j < nB) {                                                          \
          int e = __builtin_amdgcn_readlane((int)(EVB), j);                    \
          int tl = (e >> 16) & 63;                                             \
          if (tl != curRow) {                                                  \
            if (rc > 0) {                                                      \
              float sc = __builtin_amdgcn_rcpf((float)rc);                     \
              *(u32*)(aggb + (size_t)curRow * 136 + 2 * lane) =                \
                  pk2(v0 * sc, v1 * sc);                                       \
            }                                                                  \
            curRow = tl; v0 = 0.f; v1 = 0.f; rc = 0;                           \
          }                                                                    \
          v0 += __uint_as_float((XV)[j] << 16);                                \
          v1 += __uint_as_float((XV)[j] & 0xFFFF0000u);                        \
          ++rc;                                                                \
        }                                                                      \
      }                                                                        \
      for (int p = sCur + CAP; p < Er; ++p) {                                  \
        u32 e = sortedL[p];                                                    \
        u32 xvv = *(const u32*)(xb + (size_t)(e & 0xFFFFu) * 128 + 2 * lane);  \
        int tl = (int)((e >> 16) & 63);                                        \
        if (tl != curRow) {                                                    \
          if (rc > 0) {                                                        \
            float sc = __builtin_amdgcn_rcpf((float)rc);                       \
            *(u32*)(aggb + (size_t)curRow * 136 + 2 * lane) =                  \
                pk2(v0 * sc, v1 * sc);                                         \
          }                                                                    \
          curRow = tl; v0 = 0.f; v1 = 0.f; rc = 0;                             \
        }                                                                      \
        v0 += __uint_as_float(xvv << 16);                                      \
        v1 += __uint_as_float(xvv & 0xFFFF0000u);                              \
        ++rc;                                                                  \
      }                                                                        \
      if (rc > 0) {                                                            \
        float sc = __builtin_amdgcn_rcpf((float)rc);                           \
        *(u32*)(aggb + (size_t)curRow * 136 + 2 * lane) =                      \
            pk2(v0 * sc, v1 * sc);                                             \
      }                                                                        \
    }                                                                          \
    asm volatile("s_waitcnt lgkmcnt(0)" ::: "memory");                         \
    __builtin_amdgcn_sched_barrier(0);                                         \
    __builtin_amdgcn_s_barrier();                                              \
    __builtin_amdgcn_sched_barrier(0);                                         \
    short8 bfr[4][2];                                                          \
    _Pragma("unroll") for (int ks = 0; ks < 4; ++ks)                           \
      _Pragma("unroll") for (int c = 0; c < 2; ++c)                            \
        bfr[ks][c] = *(const short8*)(wp +                                     \
            ((size_t)(((r * 8 + wct0 + c) * 4 + ks) * 64 + lane)) * 8);        \
    __builtin_amdgcn_sched_barrier(0);                                         \
    if ((RI) + 2 < NRG) {                                                      \
      const int sN = __builtin_amdgcn_readlane(eAll, (RI) + 1);                \
      const int eN = __builtin_amdgcn_readlane(eAll, (RI) + 2);                \
      (EVB) = ev2;                                                             \
      const int nBn = min(eN - sN, CAP);                                       \
      _Pragma("unroll") for (int j = 0; j < CAP; ++j) {                        \
        if (j < nBn) {                                                         \
          int e = __builtin_amdgcn_readlane((int)(EVB), j);                    \
          (XV)[j] = *(const u32*)(xb + (size_t)(e & 0xFFFF) * 128 + 2 * lane); \
        }                                                                      \
      }                                                                        \
      if ((RI) + 3 < NRG) {                                                    \
        int pcn = eN + lane;                                                   \
        if (pcn > clampP) pcn = clampP;                                        \
        ev2 = sortedL[pcn];                                                    \
      }                                                                        \
    }                                                                          \
    _Pragma("unroll") for (int ks = 0; ks < 4; ++ks) {                         \
      const int kb = ks * 32 + q * 8;                                          \
      short8 af[4];                                                            \
      _Pragma("unroll") for (int rt = 0; rt < 4; ++rt)                         \
        af[rt] = *(const short8*)(aggb + (size_t)(rt * 16 + m) * 136 + kb);    \
      _Pragma("unroll") for (int c = 0; c < 2; ++c)                            \
        _Pragma("unroll") for (int rt = 0; rt < 4; ++rt)                       \
          acc[rt][c] = __builtin_amdgcn_mfma_f32_16x16x32_bf16(                \
              af[rt], bfr[ks][c], acc[rt][c], 0, 0, 0);                        \
    }                                                                          \
    asm volatile("s_waitcnt lgkmcnt(0)" ::: "memory");                         \
    __builtin_amdgcn_sched_barrier(0);                                         \
    __builtin_amdgcn_s_barrier();                                              \
    __builtin_amdgcn_sched_barrier(0);                                         \
    sCur = Er;                                                                 \
  }

__global__ __launch_bounds__(256) void k_batch(
    const u16* __restrict__ xb, const u16* __restrict__ wp, const u16* __restrict__ wrootp,
    const float* __restrict__ bias, const u32* __restrict__ bins,
    const int* __restrict__ bcnt, const int* __restrict__ inv,
    const int* __restrict__ cnt, float* __restrict__ h) {
  __shared__ u16 aggb[64 * 136];         // 17408 B
  __shared__ u32 sortedL[SORT_STRIDE];   // 4096 B (group-local sorted edges)
  __shared__ int offsL[512];             // 2048 B (key starts -> ends)
  __shared__ int wsum[4];
  const int nUsed = cnt[0] + 1;          // cnt holds last ticket (init -1)
  const int qs = blockIdx.x & (NSPLIT - 1);
  const int b = blockIdx.x >> 2;
  const int t = threadIdx.x;
  const int nb = b * 64;
  if (nb >= nUsed) return;               // uniform: before any barrier
  const int r0 = qs * NRG;
  const int lane = t & 63, w = t >> 6;
  const int m = lane & 15, q = lane >> 4;
  const int wct0 = w * 2;

  // ---- in-block counting sort of this tile's relation group ----
  const int nTile = min(bcnt[b] + 1, SORT_STRIDE);
  const u32* binB = bins + (size_t)b * SORT_STRIDE;
  offsL[t] = 0; offsL[256 + t] = 0;
  __syncthreads();
  for (int i = t; i < nTile; i += 256) {
    u32 v = binB[i];
    if ((int)(v >> 25) == qs)
      atomicAdd(&offsL[(((v >> 20) & 3) << 7) + (((v >> 22) & 7) << 4) + ((v >> 16) & 15)], 1);
  }
  __syncthreads();
  {
    int h0 = offsL[2 * t], h1 = offsL[2 * t + 1];
    int s = h0 + h1;
    int x = s;
#pragma unroll
    for (int off = 1; off < 64; off <<= 1) {
      int y = __shfl_up(x, off);
      if (lane >= off) x += y;
    }
    if (lane == 63) wsum[w] = x;
    __syncthreads();
    int wb = 0;
    for (int i = 0; i < w; ++i) wb += wsum[i];
    int ex = wb + x - s;
    offsL[2 * t] = ex;
    offsL[2 * t + 1] = ex + h0;
  }
  __syncthreads();
  for (int i = t; i < nTile; i += 256) {
    u32 v = binB[i];
    if ((int)(v >> 25) == qs) {
      int pos = atomicAdd(&offsL[(((v >> 20) & 3) << 7) + (((v >> 22) & 7) << 4) + ((v >> 16) & 15)], 1);
      sortedL[pos] = v;
    }
  }
  __syncthreads();   // offsL now per-key ENDs; sortedL group-local sorted

  const int nG = offsL[511];                       // total group edges
  const int clampP = (nG > 0) ? nG - 1 : 0;
  const int eAll = offsL[(w << 7) + ((lane & 7) << 4) + 15];  // lane rl: end of rel rl
  int sCur = (w == 0) ? 0 : offsL[(w << 7) - 1];

  const int E0 = __builtin_amdgcn_readlane(eAll, 0);
  const int E1 = __builtin_amdgcn_readlane(eAll, 1);

  // prologue: ev from LDS, depth-2 gather prefetch (global xb)
  u32 evBufA, evBufB, ev2;
  u32 xvA[CAP], xvB[CAP];
  {
    int pc = sCur + lane;
    if (pc > clampP) pc = clampP;
    evBufA = sortedL[pc];
  }
  {
    const int nB = min(E0 - sCur, CAP);
#pragma unroll
    for (int j = 0; j < CAP; ++j) {
      if (j < nB) {
        int e = __builtin_amdgcn_readlane((int)evBufA, j);
        xvA[j] = *(const u32*)(xb + (size_t)(e & 0xFFFF) * 128 + 2 * lane);
      }
    }
  }
  {
    int pc = E0 + lane;
    if (pc > clampP) pc = clampP;
    evBufB = sortedL[pc];
  }
  {
    const int nB = min(E1 - E0, CAP);
#pragma unroll
    for (int j = 0; j < CAP; ++j) {
      if (j < nB) {
        int e = __builtin_amdgcn_readlane((int)evBufB, j);
        xvB[j] = *(const u32*)(xb + (size_t)(e & 0xFFFF) * 128 + 2 * lane);
      }
    }
  }
  {
    int pc = E1 + lane;
    if (pc > clampP) pc = clampP;
    ev2 = sortedL[pc];
  }

  const short8 zero8 = {0, 0, 0, 0, 0, 0, 0, 0};
  f32x4 acc[4][2];
#pragma unroll
  for (int rt = 0; rt < 4; ++rt)
#pragma unroll
    for (int c = 0; c < 2; ++c) acc[rt][c] = (f32x4){0.f, 0.f, 0.f, 0.f};

  // root GEMM only in plane 0
  if (qs == 0) {
    int nodeR[4]; bool vR[4];
#pragma unroll
    for (int rt = 0; rt < 4; ++rt) {
      int crow = nb + rt * 16 + m;
      vR[rt] = crow < nUsed;
      nodeR[rt] = inv[vR[rt] ? crow : (nUsed - 1)];
    }
#pragma unroll
    for (int ks = 0; ks < 4; ++ks) {
      const int kb = ks * 32 + q * 8;
      short8 af[4];
#pragma unroll
      for (int rt = 0; rt < 4; ++rt)
        af[rt] = vR[rt] ? *(const short8*)(xb + (size_t)nodeR[rt] * 128 + kb) : zero8;
#pragma unroll
      for (int c = 0; c < 2; ++c) {
        short8 bf = *(const short8*)(wrootp + ((size_t)(((wct0 + c) * 4 + ks) * 64 + lane)) * 8);
#pragma unroll
        for (int rt = 0; rt < 4; ++rt)
          acc[rt][c] = __builtin_amdgcn_mfma_f32_16x16x32_bf16(af[rt], bf, acc[rt][c], 0, 0, 0);
      }
    }
  }

  for (int ri = 0; ri < NRG; ri += 2) {
    PHASE(r0 + ri, ri, xvA, evBufA)
    PHASE(r0 + ri + 1, ri + 1, xvB, evBufB)
  }

  // epilogue: (+bias in plane 0) store RAW partial plane
  float* hq = h + (size_t)qs * MAXU * 128;
#pragma unroll
  for (int c = 0; c < 2; ++c) {
    const int col = (wct0 + c) * 16 + m;
    const float bv = (qs == 0) ? bias[col] : 0.f;
#pragma unroll
    for (int rt = 0; rt < 4; ++rt) {
#pragma unroll
      for (int g = 0; g < 4; ++g) {
        const int row = nb + rt * 16 + q * 4 + g;
        if (row < nUsed) hq[(size_t)row * 128 + col] = acc[rt][c][g] + bv;
      }
    }
  }
}

// ---- K4: DistMult scoring; merge 4 partial planes + relu ----
__global__ void k_score(const float* __restrict__ h, const float* __restrict__ rel_emb,
                        const int* __restrict__ map,
                        const int* __restrict__ head, const int* __restrict__ tail,
                        const int* __restrict__ rel, float* __restrict__ out, int T) {
  int lane = threadIdx.x & 63, w = threadIdx.x >> 6;
  int gid = blockIdx.x * 4 + w;
  if (gid >= T) return;
  const int hr = map[head[gid]];
  const int tr = map[tail[gid]];
  const size_t ho = (size_t)hr * 128 + 2 * lane;
  const size_t to = (size_t)tr * 128 + 2 * lane;
  float hx = 0.f, hy = 0.f, tx = 0.f, ty = 0.f;
#pragma unroll
  for (int s = 0; s < NSPLIT; ++s) {
    const float2 a = *(const float2*)(h + (size_t)s * (MAXU * 128) + ho);
    const float2 c = *(const float2*)(h + (size_t)s * (MAXU * 128) + to);
    hx += a.x; hy += a.y; tx += c.x; ty += c.y;
  }
  hx = hx > 0.f ? hx : 0.f;
  hy = hy > 0.f ? hy : 0.f;
  tx = tx > 0.f ? tx : 0.f;
  ty = ty > 0.f ? ty : 0.f;
  const float2 r2 = *(const float2*)(rel_emb + (size_t)rel[gid] * 128 + 2 * lane);
  float s = hx * r2.x * tx + hy * r2.y * ty;
#pragma unroll
  for (int off = 32; off > 0; off >>= 1) s += __shfl_down(s, off);
  if (lane == 0) out[gid] = s;
}

extern "C" void kernel_launch(void* const* d_in, const int* in_sizes, int n_in,
                              void* d_out, int out_size, void* d_ws, size_t ws_size,
                              hipStream_t stream) {
  const float* x     = (const float*)d_in[0];
  const float* W     = (const float*)d_in[1];
  const float* Wroot = (const float*)d_in[2];
  const float* bias  = (const float*)d_in[3];
  const float* relE  = (const float*)d_in[4];
  const int* ei      = (const int*)d_in[5];
  const int* et      = (const int*)d_in[6];
  const int* headI   = (const int*)d_in[7];
  const int* tailI   = (const int*)d_in[8];
  const int* relI    = (const int*)d_in[9];
  float* out = (float*)d_out;

  const int N = in_sizes[0] / 128;   // 50000
  const int E = in_sizes[6];         // 600000
  const int T = in_sizes[7];         // 8192
  const int NB2 = MAXU / 64;         // 256 compact tiles (worst case)

  char* p = (char*)d_ws;
  auto alloc = [&](size_t bytes) -> void* {
    void* r = (void*)p;
    p += (bytes + 255) & ~(size_t)255;
    return r;
  };
  u16* xb     = (u16*)alloc((size_t)N * 128 * 2);           // 12.8 MB
  u16* wp     = (u16*)alloc((size_t)32 * 2048 * 8 * 2);     // 1 MB
  u16* wrootp = (u16*)alloc((size_t)2048 * 8 * 2);
  // one 0xFF region: map (N) + cnt + bcnt (NB2), all init -1
  int* map    = (int*)alloc((size_t)(N + 64 + NB2) * 4);
  int* cnt    = map + N;
  int* bcnt   = map + N + 64;
  int* inv    = (int*)alloc((size_t)MAXU * 4);              // 64 KB
  u32* bins   = (u32*)alloc((size_t)NB2 * SORT_STRIDE * 4); // 1 MB
  float* h    = (float*)alloc((size_t)NSPLIT * MAXU * 128 * 4); // 33.5 MB

  const int n4 = N * 128 / 4;
  const int convNB = (n4 + 255) / 256;
  const int markNB = (2 * T + 255) / 256;

  hipMemsetAsync(map, 0xFF, (size_t)(N + 64 + NB2) * 4, stream);  // map/cnt/bcnt = -1
  k_prep<<<convNB + 33 + markNB, 256, 0, stream>>>(
      x, W, Wroot, xb, wp, wrootp, headI, tailI, map, inv, cnt, n4, convNB, T);
  k_bin<<<(E + 255) / 256, 256, 0, stream>>>(ei, et, map, bcnt, bins, E);
  k_batch<<<NB2 * NSPLIT, 256, 0, stream>>>(xb, wp, wrootp, bias, bins, bcnt, inv, cnt, h);
  k_score<<<(T + 3) / 4, 256, 0, stream>>>(h, relE, map, headI, tailI, relI, out, T);
}

// Round 12
// 170.357 us; speedup vs baseline: 1.7766x; 1.7766x over previous
//
#include <hip/hip_runtime.h>
#include <hip/hip_bf16.h>

typedef unsigned int u32;
typedef unsigned short u16;
typedef short short8 __attribute__((ext_vector_type(8)));
typedef float f32x4 __attribute__((ext_vector_type(4)));

#define R_ 32
#define BSTRIDE 64          // per-(tile,rel) bucket slots (lambda~24, +8 sigma)
#define CAP 12              // per-wave per-relation buffered gathers (mean ~6)
#define MAXU 16384          // max unique scored nodes (2*T)
#define NSPLIT 4            // relation-group split
#define NRG 8               // relations per group (R_/NSPLIT)

static __device__ __forceinline__ u16 f2bf(float f) {
  u32 u = __float_as_uint(f);
  u = (u + 0x7FFFu + ((u >> 16) & 1u)) >> 16;   // RNE
  return (u16)u;
}
static __device__ __forceinline__ u32 pk2(float a, float b) {
  __hip_bfloat162 h2 = __float22bfloat162_rn(make_float2(a, b));
  union { __hip_bfloat162 h; u32 u; } cv; cv.h = h2; return cv.u;
}

// ---- K1: x convert + W pack (LDS transpose) + mark/compact ----
// map pre-filled -1, cnt pre-filled -1, bcnt pre-filled -1 (one 0xFF memset).
__global__ __launch_bounds__(256) void k_prep(
    const float* __restrict__ x, const float* __restrict__ W,
    const float* __restrict__ Wroot, u16* __restrict__ xb,
    u16* __restrict__ wp, u16* __restrict__ wrootp,
    const int* __restrict__ head, const int* __restrict__ tail,
    int* __restrict__ map, int* __restrict__ inv, int* __restrict__ cnt,
    int n4, int convNB, int T) {
  __shared__ u32 lds[8192];   // 32 KB: one 128x128 bf16 matrix
  int bx = blockIdx.x;
  const int t = threadIdx.x;
  if (bx < convNB) {
    int i = bx * 256 + t;
    if (i >= n4) return;
    const float4 f = ((const float4*)x)[i];
    u32 lo = (u32)f2bf(f.x) | ((u32)f2bf(f.y) << 16);
    u32 hi = (u32)f2bf(f.z) | ((u32)f2bf(f.w) << 16);
    ((uint2*)xb)[i] = make_uint2(lo, hi);
    return;
  }
  bx -= convNB;
  if (bx < 33) {
    const int rr = bx;
    const float* src = (rr < 32) ? (W + (size_t)rr * (128 * 128)) : Wroot;
#pragma unroll
    for (int k = 0; k < 16; ++k) {
      const int fi = k * 256 + t;
      const float4 f = ((const float4*)src)[fi];
      u32 lo = (u32)f2bf(f.x) | ((u32)f2bf(f.y) << 16);
      u32 hi = (u32)f2bf(f.z) | ((u32)f2bf(f.w) << 16);
      ((uint2*)lds)[fi] = make_uint2(lo, hi);
    }
    __syncthreads();
    const u16* l16 = (const u16*)lds;
#pragma unroll
    for (int p = 0; p < 8; ++p) {
      const int v = p * 256 + t;
      const int lane = v & 63, ks = (v >> 6) & 3, ct = v >> 8;
      const int i0 = ks * 32 + (lane >> 4) * 8;
      const int o  = ct * 16 + (lane & 15);
      u32 w01 = (u32)l16[(i0 + 0) * 128 + o] | ((u32)l16[(i0 + 1) * 128 + o] << 16);
      u32 w23 = (u32)l16[(i0 + 2) * 128 + o] | ((u32)l16[(i0 + 3) * 128 + o] << 16);
      u32 w45 = (u32)l16[(i0 + 4) * 128 + o] | ((u32)l16[(i0 + 5) * 128 + o] << 16);
      u32 w67 = (u32)l16[(i0 + 6) * 128 + o] | ((u32)l16[(i0 + 7) * 128 + o] << 16);
      u16* dst = (rr < 32) ? (wp + ((size_t)((rr * 8 + ct) * 4 + ks) * 64 + lane) * 8)
                           : (wrootp + ((size_t)((ct * 4 + ks) * 64 + lane)) * 8);
      *(uint4*)dst = make_uint4(w01, w23, w45, w67);
    }
    return;
  }
  bx -= 33;
  int i = bx * 256 + t;
  if (i >= 2 * T) return;
  int n = (i < T) ? head[i] : tail[i - T];
  if (atomicCAS(map + n, -1, -2) == -1) {
    int c = atomicAdd(cnt, 1) + 1;   // cnt starts at -1 -> first ticket 0
    inv[c] = n;
    map[n] = c;
  }
}

// ---- K2: bin kept edges into per-(tile,relation) buckets ----
// 8192 counters (lambda~24 each) -> no same-address atomic pileup.
// packed: src(16b) | row-in-tile(6b)<<16 | rel(5b)<<22.  bcnt init -1.
__global__ void k_bin(const int* __restrict__ ei, const int* __restrict__ et,
                      const int* __restrict__ map,
                      int* __restrict__ bcnt, u32* __restrict__ bins, int E) {
  int e = blockIdx.x * 256 + threadIdx.x;
  if (e >= E) return;
  int mt = map[ei[E + e]];
  if (mt < 0) return;
  int r = et[e];
  int bkt = (mt >> 6) * R_ + r;
  int p = atomicAdd(bcnt + bkt, 1) + 1;
  if (p < BSTRIDE)
    bins[((size_t)bkt << 6) + p] =
        ((u32)ei[e] & 0xFFFFu) | ((u32)(mt & 63) << 16) | ((u32)r << 22);
}

// ---- K3: batch kernel with IN-BLOCK LDS counting sort ----
// Block (b, qs): tile b (64 compact nodes) x relation group qs (8 rels).
// Its 8 relation buckets are CONTIGUOUS: bins[(b*32+r0)*64 .. +512).
// 1) load 512 slots (valid = slot < cnt), LDS-hist keys (wg,rl,row),
//    wave-scan, LDS-scatter into sortedL (group-local sorted order).
// 2) round-7 phase loop; edge reads from LDS sortedL.
#define PHASE(RR, RI, XV, EVB)                                                 \
  {                                                                            \
    const int r = (RR);                                                        \
    const int Er = __builtin_amdgcn_readlane(eAll, (RI));                      \
    _Pragma("unroll") for (int rr = 0; rr < 16; ++rr)                          \
        *(u32*)(aggb + (size_t)(w * 16 + rr) * 136 + 2 * lane) = 0;            \
    {                                                                          \
      const int nB = min(Er - sCur, CAP);                                      \
      int curRow = -1, rc = 0;                                                 \
      float v0 = 0.f, v1 = 0.f;                                                \
      _Pragma("unroll") for (int j = 0; j < CAP; ++j) {                        \
        if (j < nB) {                                                          \
          int e = __builtin_amdgcn_readlane((int)(EVB), j);                    \
          int tl = (e >> 16) & 63;                                             \
          if (tl != curRow) {                                                  \
            if (rc > 0) {                                                      \
              float sc = __builtin_amdgcn_rcpf((float)rc);                     \
              *(u32*)(aggb + (size_t)curRow * 136 + 2 * lane) =                \
                  pk2(v0 * sc, v1 * sc);                                       \
            }                                                                  \
            curRow = tl; v0 = 0.f; v1 = 0.f; rc = 0;                           \
          }                                                                    \
          v0 += __uint_as_float((XV)[j] << 16);                                \
          v1 += __uint_as_float((XV)[j] & 0xFFFF0000u);                        \
          ++rc;                                                                \
        }                                                                      \
      }                                                                        \
      for (int p = sCur + CAP; p < Er; ++p) {                                  \
        u32 e = sortedL[p];                                                    \
        u32 xvv = *(const u32*)(xb + (size_t)(e & 0xFFFFu) * 128 + 2 * lane);  \
        int tl = (int)((e >> 16) & 63);                                        \
        if (tl != curRow) {                                                    \
          if (rc > 0) {                                                        \
            float sc = __builtin_amdgcn_rcpf((float)rc);                       \
            *(u32*)(aggb + (size_t)curRow * 136 + 2 * lane) =                  \
                pk2(v0 * sc, v1 * sc);                                         \
          }                                                                    \
          curRow = tl; v0 = 0.f; v1 = 0.f; rc = 0;                             \
        }                                                                      \
        v0 += __uint_as_float(xvv << 16);                                      \
        v1 += __uint_as_float(xvv & 0xFFFF0000u);                              \
        ++rc;                                                                  \
      }                                                                        \
      if (rc > 0) {                                                            \
        float sc = __builtin_amdgcn_rcpf((float)rc);                           \
        *(u32*)(aggb + (size_t)curRow * 136 + 2 * lane) =                      \
            pk2(v0 * sc, v1 * sc);                                             \
      }                                                                        \
    }                                                                          \
    asm volatile("s_waitcnt lgkmcnt(0)" ::: "memory");                         \
    __builtin_amdgcn_sched_barrier(0);                                         \
    __builtin_amdgcn_s_barrier();                                              \
    __builtin_amdgcn_sched_barrier(0);                                         \
    short8 bfr[4][2];                                                          \
    _Pragma("unroll") for (int ks = 0; ks < 4; ++ks)                           \
      _Pragma("unroll") for (int c = 0; c < 2; ++c)                            \
        bfr[ks][c] = *(const short8*)(wp +                                     \
            ((size_t)(((r * 8 + wct0 + c) * 4 + ks) * 64 + lane)) * 8);        \
    __builtin_amdgcn_sched_barrier(0);                                         \
    if ((RI) + 2 < NRG) {                                                      \
      const int sN = __builtin_amdgcn_readlane(eAll, (RI) + 1);                \
      const int eN = __builtin_amdgcn_readlane(eAll, (RI) + 2);                \
      (EVB) = ev2;                                                             \
      const int nBn = min(eN - sN, CAP);                                       \
      _Pragma("unroll") for (int j = 0; j < CAP; ++j) {                        \
        if (j < nBn) {                                                         \
          int e = __builtin_amdgcn_readlane((int)(EVB), j);                    \
          (XV)[j] = *(const u32*)(xb + (size_t)(e & 0xFFFF) * 128 + 2 * lane); \
        }                                                                      \
      }                                                                        \
      if ((RI) + 3 < NRG) {                                                    \
        int pcn = eN + lane;                                                   \
        if (pcn > clampP) pcn = clampP;                                        \
        ev2 = sortedL[pcn];                                                    \
      }                                                                        \
    }                                                                          \
    _Pragma("unroll") for (int ks = 0; ks < 4; ++ks) {                         \
      const int kb = ks * 32 + q * 8;                                          \
      short8 af[4];                                                            \
      _Pragma("unroll") for (int rt = 0; rt < 4; ++rt)                         \
        af[rt] = *(const short8*)(aggb + (size_t)(rt * 16 + m) * 136 + kb);    \
      _Pragma("unroll") for (int c = 0; c < 2; ++c)                            \
        _Pragma("unroll") for (int rt = 0; rt < 4; ++rt)                       \
          acc[rt][c] = __builtin_amdgcn_mfma_f32_16x16x32_bf16(                \
              af[rt], bfr[ks][c], acc[rt][c], 0, 0, 0);                        \
    }                                                                          \
    asm volatile("s_waitcnt lgkmcnt(0)" ::: "memory");                         \
    __builtin_amdgcn_sched_barrier(0);                                         \
    __builtin_amdgcn_s_barrier();                                              \
    __builtin_amdgcn_sched_barrier(0);                                         \
    sCur = Er;                                                                 \
  }

__global__ __launch_bounds__(256) void k_batch(
    const u16* __restrict__ xb, const u16* __restrict__ wp, const u16* __restrict__ wrootp,
    const float* __restrict__ bias, const u32* __restrict__ bins,
    const int* __restrict__ bcnt, const int* __restrict__ inv,
    const int* __restrict__ cnt, float* __restrict__ h) {
  __shared__ u16 aggb[64 * 136];         // 17408 B
  __shared__ u32 sortedL[512];           // 2048 B (group-local sorted edges)
  __shared__ int offsL[512];             // 2048 B (key starts -> ends)
  __shared__ int wsum[4];
  const int nUsed = cnt[0] + 1;          // cnt holds last ticket (init -1)
  const int qs = blockIdx.x & (NSPLIT - 1);
  const int b = blockIdx.x >> 2;
  const int t = threadIdx.x;
  const int nb = b * 64;
  if (nb >= nUsed) return;               // uniform: before any barrier
  const int r0 = qs * NRG;
  const int lane = t & 63, w = t >> 6;
  const int m = lane & 15, q = lane >> 4;
  const int wct0 = w * 2;

  // ---- in-block counting sort: 512 contiguous bucket slots -> sortedL ----
  offsL[t] = 0; offsL[256 + t] = 0;
  __syncthreads();
  const u32* binG = bins + (((size_t)b * R_ + r0) << 6);
  u32 eV[2]; bool okV[2];
#pragma unroll
  for (int p2 = 0; p2 < 2; ++p2) {
    const int i = p2 * 256 + t;
    const int rl = i >> 6, slot = i & 63;
    const int cr = min(bcnt[b * R_ + r0 + rl] + 1, BSTRIDE);
    u32 v = binG[i];
    bool ok = slot < cr;
    eV[p2] = v; okV[p2] = ok;
    if (ok)
      atomicAdd(&offsL[(((v >> 20) & 3) << 7) + (((v >> 22) & 7) << 4) + ((v >> 16) & 15)], 1);
  }
  __syncthreads();
  {
    int h0 = offsL[2 * t], h1 = offsL[2 * t + 1];
    int s = h0 + h1;
    int x = s;
#pragma unroll
    for (int off = 1; off < 64; off <<= 1) {
      int y = __shfl_up(x, off);
      if (lane >= off) x += y;
    }
    if (lane == 63) wsum[w] = x;
    __syncthreads();
    int wb = 0;
    for (int i = 0; i < w; ++i) wb += wsum[i];
    int ex = wb + x - s;
    offsL[2 * t] = ex;
    offsL[2 * t + 1] = ex + h0;
  }
  __syncthreads();
#pragma unroll
  for (int p2 = 0; p2 < 2; ++p2) {
    if (okV[p2]) {
      u32 v = eV[p2];
      int pos = atomicAdd(&offsL[(((v >> 20) & 3) << 7) + (((v >> 22) & 7) << 4) + ((v >> 16) & 15)], 1);
      sortedL[pos] = v;
    }
  }
  __syncthreads();   // offsL now per-key ENDs; sortedL group-local sorted

  const int nG = offsL[511];                       // total group edges
  const int clampP = (nG > 0) ? nG - 1 : 0;
  const int eAll = offsL[(w << 7) + ((lane & 7) << 4) + 15];  // lane rl: end of rel rl
  int sCur = (w == 0) ? 0 : offsL[(w << 7) - 1];

  const int E0 = __builtin_amdgcn_readlane(eAll, 0);
  const int E1 = __builtin_amdgcn_readlane(eAll, 1);

  // prologue: ev from LDS, depth-2 gather prefetch (global xb)
  u32 evBufA, evBufB, ev2;
  u32 xvA[CAP], xvB[CAP];
  {
    int pc = sCur + lane;
    if (pc > clampP) pc = clampP;
    evBufA = sortedL[pc];
  }
  {
    const int nB = min(E0 - sCur, CAP);
#pragma unroll
    for (int j = 0; j < CAP; ++j) {
      if (j < nB) {
        int e = __builtin_amdgcn_readlane((int)evBufA, j);
        xvA[j] = *(const u32*)(xb + (size_t)(e & 0xFFFF) * 128 + 2 * lane);
      }
    }
  }
  {
    int pc = E0 + lane;
    if (pc > clampP) pc = clampP;
    evBufB = sortedL[pc];
  }
  {
    const int nB = min(E1 - E0, CAP);
#pragma unroll
    for (int j = 0; j < CAP; ++j) {
      if (j < nB) {
        int e = __builtin_amdgcn_readlane((int)evBufB, j);
        xvB[j] = *(const u32*)(xb + (size_t)(e & 0xFFFF) * 128 + 2 * lane);
      }
    }
  }
  {
    int pc = E1 + lane;
    if (pc > clampP) pc = clampP;
    ev2 = sortedL[pc];
  }

  const short8 zero8 = {0, 0, 0, 0, 0, 0, 0, 0};
  f32x4 acc[4][2];
#pragma unroll
  for (int rt = 0; rt < 4; ++rt)
#pragma unroll
    for (int c = 0; c < 2; ++c) acc[rt][c] = (f32x4){0.f, 0.f, 0.f, 0.f};

  // root GEMM only in plane 0
  if (qs == 0) {
    int nodeR[4]; bool vR[4];
#pragma unroll
    for (int rt = 0; rt < 4; ++rt) {
      int crow = nb + rt * 16 + m;
      vR[rt] = crow < nUsed;
      nodeR[rt] = inv[vR[rt] ? crow : (nUsed - 1)];
    }
#pragma unroll
    for (int ks = 0; ks < 4; ++ks) {
      const int kb = ks * 32 + q * 8;
      short8 af[4];
#pragma unroll
      for (int rt = 0; rt < 4; ++rt)
        af[rt] = vR[rt] ? *(const short8*)(xb + (size_t)nodeR[rt] * 128 + kb) : zero8;
#pragma unroll
      for (int c = 0; c < 2; ++c) {
        short8 bf = *(const short8*)(wrootp + ((size_t)(((wct0 + c) * 4 + ks) * 64 + lane)) * 8);
#pragma unroll
        for (int rt = 0; rt < 4; ++rt)
          acc[rt][c] = __builtin_amdgcn_mfma_f32_16x16x32_bf16(af[rt], bf, acc[rt][c], 0, 0, 0);
      }
    }
  }

  for (int ri = 0; ri < NRG; ri += 2) {
    PHASE(r0 + ri, ri, xvA, evBufA)
    PHASE(r0 + ri + 1, ri + 1, xvB, evBufB)
  }

  // epilogue: (+bias in plane 0) store RAW partial plane
  float* hq = h + (size_t)qs * MAXU * 128;
#pragma unroll
  for (int c = 0; c < 2; ++c) {
    const int col = (wct0 + c) * 16 + m;
    const float bv = (qs == 0) ? bias[col] : 0.f;
#pragma unroll
    for (int rt = 0; rt < 4; ++rt) {
#pragma unroll
      for (int g = 0; g < 4; ++g) {
        const int row = nb + rt * 16 + q * 4 + g;
        if (row < nUsed) hq[(size_t)row * 128 + col] = acc[rt][c][g] + bv;
      }
    }
  }
}

// ---- K4: DistMult scoring; merge 4 partial planes + relu ----
__global__ void k_score(const float* __restrict__ h, const float* __restrict__ rel_emb,
                        const int* __restrict__ map,
                        const int* __restrict__ head, const int* __restrict__ tail,
                        const int* __restrict__ rel, float* __restrict__ out, int T) {
  int lane = threadIdx.x & 63, w = threadIdx.x >> 6;
  int gid = blockIdx.x * 4 + w;
  if (gid >= T) return;
  const int hr = map[head[gid]];
  const int tr = map[tail[gid]];
  const size_t ho = (size_t)hr * 128 + 2 * lane;
  const size_t to = (size_t)tr * 128 + 2 * lane;
  float hx = 0.f, hy = 0.f, tx = 0.f, ty = 0.f;
#pragma unroll
  for (int s = 0; s < NSPLIT; ++s) {
    const float2 a = *(const float2*)(h + (size_t)s * (MAXU * 128) + ho);
    const float2 c = *(const float2*)(h + (size_t)s * (MAXU * 128) + to);
    hx += a.x; hy += a.y; tx += c.x; ty += c.y;
  }
  hx = hx > 0.f ? hx : 0.f;
  hy = hy > 0.f ? hy : 0.f;
  tx = tx > 0.f ? tx : 0.f;
  ty = ty > 0.f ? ty : 0.f;
  const float2 r2 = *(const float2*)(rel_emb + (size_t)rel[gid] * 128 + 2 * lane);
  float s = hx * r2.x * tx + hy * r2.y * ty;
#pragma unroll
  for (int off = 32; off > 0; off >>= 1) s += __shfl_down(s, off);
  if (lane == 0) out[gid] = s;
}

extern "C" void kernel_launch(void* const* d_in, const int* in_sizes, int n_in,
                              void* d_out, int out_size, void* d_ws, size_t ws_size,
                              hipStream_t stream) {
  const float* x     = (const float*)d_in[0];
  const float* W     = (const float*)d_in[1];
  const float* Wroot = (const float*)d_in[2];
  const float* bias  = (const float*)d_in[3];
  const float* relE  = (const float*)d_in[4];
  const int* ei      = (const int*)d_in[5];
  const int* et      = (const int*)d_in[6];
  const int* headI   = (const int*)d_in[7];
  const int* tailI   = (const int*)d_in[8];
  const int* relI    = (const int*)d_in[9];
  float* out = (float*)d_out;

  const int N = in_sizes[0] / 128;   // 50000
  const int E = in_sizes[6];         // 600000
  const int T = in_sizes[7];         // 8192
  const int NB2 = MAXU / 64;         // 256 compact tiles (worst case)
  const int NBKT = NB2 * R_;         // 8192 buckets

  char* p = (char*)d_ws;
  auto alloc = [&](size_t bytes) -> void* {
    void* r = (void*)p;
    p += (bytes + 255) & ~(size_t)255;
    return r;
  };
  u16* xb     = (u16*)alloc((size_t)N * 128 * 2);           // 12.8 MB
  u16* wp     = (u16*)alloc((size_t)32 * 2048 * 8 * 2);     // 1 MB
  u16* wrootp = (u16*)alloc((size_t)2048 * 8 * 2);
  // one 0xFF region: map (N) + cnt + bcnt (NBKT), all init -1
  int* map    = (int*)alloc((size_t)(N + 64 + NBKT) * 4);
  int* cnt    = map + N;
  int* bcnt   = map + N + 64;
  int* inv    = (int*)alloc((size_t)MAXU * 4);              // 64 KB
  u32* bins   = (u32*)alloc((size_t)NBKT * BSTRIDE * 4);    // 2 MB
  float* h    = (float*)alloc((size_t)NSPLIT * MAXU * 128 * 4); // 33.5 MB

  const int n4 = N * 128 / 4;
  const int convNB = (n4 + 255) / 256;
  const int markNB = (2 * T + 255) / 256;

  hipMemsetAsync(map, 0xFF, (size_t)(N + 64 + NBKT) * 4, stream);  // map/cnt/bcnt = -1
  k_prep<<<convNB + 33 + markNB, 256, 0, stream>>>(
      x, W, Wroot, xb, wp, wrootp, headI, tailI, map, inv, cnt, n4, convNB, T);
  k_bin<<<(E + 255) / 256, 256, 0, stream>>>(ei, et, map, bcnt, bins, E);
  k_batch<<<NB2 * NSPLIT, 256, 0, stream>>>(xb, wp, wrootp, bias, bins, bcnt, inv, cnt, h);
  k_score<<<(T + 3) / 4, 256, 0, stream>>>(h, relE, map, headI, tailI, relI, out, T);
}